// Round 1
// baseline (629.193 us; speedup 1.0000x reference)
//
#include <hip/hip_runtime.h>
#include <math.h>

#define T_ 512
#define B_ 32
#define C_ 6000
#define L_ 32
#define S_ 65      // 2L+1 extended states
#define SP_ 68     // padded row stride in floats (272 B = 16B-aligned)
#define NEGV (-1e30f)

// Kernel 1: per (t,b) row of C=6000: online-softmax logsumexp, then gather the
// S extended-label classes as log-probs into lpext[(b*T + t)*SP + s].
__global__ __launch_bounds__(256) void k_lse_gather(
    const float* __restrict__ x, const int* __restrict__ label,
    float* __restrict__ lpext)
{
    const int blk = blockIdx.x;        // t*B + b
    const int t = blk / B_;
    const int b = blk - t * B_;
    const float* row = x + (size_t)blk * C_;
    const int tid = threadIdx.x;

    // online softmax over the row (C_ = 6000 = 1500 float4, coalesced)
    float m = NEGV, s = 0.f;
    const float4* row4 = (const float4*)row;
    for (int i = tid; i < C_ / 4; i += 256) {
        float4 v = row4[i];
        float xm = fmaxf(fmaxf(v.x, v.y), fmaxf(v.z, v.w));
        float nm = fmaxf(m, xm);
        s = s * __expf(m - nm)
          + __expf(v.x - nm) + __expf(v.y - nm)
          + __expf(v.z - nm) + __expf(v.w - nm);
        m = nm;
    }

    // wave-level (64) reduce of (m, s)
    for (int off = 32; off > 0; off >>= 1) {
        float om = __shfl_down(m, off, 64);
        float os = __shfl_down(s, off, 64);
        float nm = fmaxf(m, om);
        s = s * __expf(m - nm) + os * __expf(om - nm);
        m = nm;
    }

    // cross-wave (4 waves) reduce via LDS
    __shared__ float wm[4], wsum[4];
    __shared__ float s_lse;
    const int wave = tid >> 6, lane = tid & 63;
    if (lane == 0) { wm[wave] = m; wsum[wave] = s; }
    __syncthreads();
    if (tid == 0) {
        float M = wm[0], Ssum = wsum[0];
        for (int w = 1; w < 4; ++w) {
            float nm = fmaxf(M, wm[w]);
            Ssum = Ssum * __expf(M - nm) + wsum[w] * __expf(wm[w] - nm);
            M = nm;
        }
        s_lse = M + __logf(Ssum);
    }
    __syncthreads();
    const float lse = s_lse;

    // gather extended-label classes: s even -> blank(0); s odd -> label[(s-1)/2]+1
    if (tid < S_) {
        int cls = 0;
        if (tid & 1) {
            int lv = label[b * L_ + (tid >> 1)];   // tid odd: tid>>1 == (tid-1)/2
            cls = (lv >= 0) ? (lv + 1) : 0;
        }
        lpext[((size_t)b * T_ + t) * SP_ + tid] = row[cls] - lse;
    }
}

// Kernel 2: CTC forward (alpha) recursion. One block per batch element.
// lp staged to LDS in chunks of 64 timesteps; alpha double-buffered in LDS.
__global__ __launch_bounds__(128) void k_alpha(
    const float* __restrict__ lpext, const int* __restrict__ label,
    float* __restrict__ losses)
{
    const int b = blockIdx.x;
    const int tid = threadIdx.x;

    __shared__ float cb[64 * SP_];     // 17,408 B chunk of log-probs
    __shared__ float A[2][S_ + 1];     // double-buffered alpha
    __shared__ int lab[L_];
    __shared__ int s_len;

    if (tid < L_) {
        int lv = label[b * L_ + tid];
        lab[tid] = (lv >= 0) ? (lv + 1) : 0;
    }
    if (tid == 0) {
        int n = 0;
        for (int j = 0; j < L_; ++j) n += (label[b * L_ + j] >= 0) ? 1 : 0;
        s_len = n;
    }
    __syncthreads();

    // per-thread skip-allowed flag (odd s >= 3 with distinct neighbors)
    bool allow = false;
    if (tid < S_ && (tid & 1) && tid >= 3) {
        int j = tid >> 1;
        allow = (lab[j] != lab[j - 1]);
    }
    const int len = s_len;

    const float* base = lpext + (size_t)b * T_ * SP_;
    int cur = 0;

    for (int c = 0; c < 8; ++c) {
        // stage chunk c: timesteps [c*64, c*64+64), contiguous & 16B-aligned
        const float4* src = (const float4*)(base + (size_t)c * 64 * SP_);
        float4* dst = (float4*)cb;
        for (int i = tid; i < 64 * SP_ / 4; i += 128) dst[i] = src[i];
        __syncthreads();

        if (c == 0) {
            if (tid < S_) {
                float v = NEGV;
                if (tid == 0) v = cb[0];
                else if (tid == 1 && len > 0) v = cb[1];
                A[0][tid] = v;
            }
            cur = 0;
            __syncthreads();
        }

        const int tt0 = (c == 0) ? 1 : 0;
        for (int tt = tt0; tt < 64; ++tt) {
            if (tid < S_) {
                float a1 = A[cur][tid];
                float a2 = (tid >= 1) ? A[cur][tid - 1] : NEGV;
                float a3 = allow ? A[cur][tid - 2] : NEGV;
                float mm = fmaxf(fmaxf(a1, a2), a3);
                float sum = __expf(a1 - mm) + __expf(a2 - mm) + __expf(a3 - mm);
                A[cur ^ 1][tid] = mm + __logf(sum) + cb[tt * SP_ + tid];
            }
            __syncthreads();
            cur ^= 1;
        }
    }

    if (tid == 0) {
        int se = 2 * len;
        float l1 = A[cur][se];
        float l2 = (len > 0) ? A[cur][se - 1] : NEGV;
        float mm = fmaxf(l1, l2);
        float loss = -(mm + __logf(__expf(l1 - mm) + __expf(l2 - mm)));
        if (!(loss < 1e29f)) loss = 0.f;   // zero_infinity
        losses[b] = loss;
    }
}

// Kernel 3: mean over B then / L  ->  sum / (B*L)
__global__ __launch_bounds__(64) void k_reduce(
    const float* __restrict__ losses, float* __restrict__ out)
{
    const int tid = threadIdx.x;
    float v = (tid < B_) ? losses[tid] : 0.f;
    for (int off = 32; off > 0; off >>= 1) v += __shfl_down(v, off, 64);
    if (tid == 0) out[0] = v / (float)(B_ * L_);
}

extern "C" void kernel_launch(void* const* d_in, const int* in_sizes, int n_in,
                              void* d_out, int out_size, void* d_ws, size_t ws_size,
                              hipStream_t stream)
{
    const float* x = (const float*)d_in[0];
    const int* label = (const int*)d_in[1];
    float* out = (float*)d_out;

    float* lpext = (float*)d_ws;                          // B*T*SP floats (~4.5 MB)
    float* losses = lpext + (size_t)B_ * T_ * SP_;        // B floats

    k_lse_gather<<<T_ * B_, 256, 0, stream>>>(x, label, lpext);
    k_alpha<<<B_, 128, 0, stream>>>(lpext, label, losses);
    k_reduce<<<1, 64, 0, stream>>>(losses, out);
}